// Round 11
// baseline (185.887 us; speedup 1.0000x reference)
//
#include <hip/hip_runtime.h>

// GCN 2-layer, N=200000, E=3200000.
// R10 post-mortem: 171us spread over 6 sub-30us kernels; no single bottleneck.
// R11: delete the hist+scan passes entirely by padding — each (bucket, block)
// pair owns a fixed 64-entry cell, so k_bin needs no global offsets (one pass
// over edges). k_build compacts cells wave-per-cell, then counts/scans/sorts
// in LDS (as R10) and writes the sorted adjacency back coalesced.
// 4 launches: bin -> build -> agg1 -> agg2.

#define BSE   512    // bin block size
#define CH    8192   // edges per bin block
#define NBW   512    // nodes per bucket
#define SH    9      // log2(NBW)
#define NB    391    // buckets = ceil(200000/512); also bin blocks = ceil(E/CH)
#define CCAP  64     // cell capacity: Binomial(8192,1/391) mean 21, +9.4 sigma
#define SLAB  (NB * CCAP)          // words per bucket slab = 25024
#define FCAP  9216   // LDS stage capacity (bucket mean 8184, +11 sigma)
#define BSB   512    // build block size
#define RSTG  ((FCAP + BSB - 1) / BSB)   // 18 staging regs

// P1: single-pass bin. Each block b owns cell (k,b) for every bucket k.
__global__ void k_bin(const int* __restrict__ src, const int* __restrict__ dst,
                      int E, unsigned* __restrict__ epack,
                      unsigned* __restrict__ cellcnt) {
    __shared__ unsigned cur[NB];
    int b = blockIdx.x, t = threadIdx.x;
    for (int i = t; i < NB; i += BSE) cur[i] = 0;
    __syncthreads();
    int lo = b * CH, hi = min(E, lo + CH);
    int aligned = (hi - lo) & ~3;
    for (int i = lo + 4 * t; i + 3 < hi; i += 4 * BSE) {
        int4 d4 = *(const int4*)(dst + i);
        int4 s4 = *(const int4*)(src + i);
        unsigned k0 = ((unsigned)d4.x) >> SH, k1 = ((unsigned)d4.y) >> SH;
        unsigned k2 = ((unsigned)d4.z) >> SH, k3 = ((unsigned)d4.w) >> SH;
        unsigned p0 = atomicAdd(&cur[k0], 1u);
        unsigned p1 = atomicAdd(&cur[k1], 1u);
        unsigned p2 = atomicAdd(&cur[k2], 1u);
        unsigned p3 = atomicAdd(&cur[k3], 1u);
        if (p0 < CCAP) epack[((size_t)k0 * NB + b) * CCAP + p0] =
            ((unsigned)s4.x << SH) | (((unsigned)d4.x) & (NBW - 1u));
        if (p1 < CCAP) epack[((size_t)k1 * NB + b) * CCAP + p1] =
            ((unsigned)s4.y << SH) | (((unsigned)d4.y) & (NBW - 1u));
        if (p2 < CCAP) epack[((size_t)k2 * NB + b) * CCAP + p2] =
            ((unsigned)s4.z << SH) | (((unsigned)d4.z) & (NBW - 1u));
        if (p3 < CCAP) epack[((size_t)k3 * NB + b) * CCAP + p3] =
            ((unsigned)s4.w << SH) | (((unsigned)d4.w) & (NBW - 1u));
    }
    for (int i = lo + aligned + t; i < hi; i += BSE) {
        unsigned d = (unsigned)dst[i];
        unsigned k = d >> SH;
        unsigned pos = atomicAdd(&cur[k], 1u);
        if (pos < CCAP)
            epack[((size_t)k * NB + b) * CCAP + pos] =
                ((unsigned)src[i] << SH) | (d & (NBW - 1u));
    }
    __syncthreads();
    for (int i = t; i < NB; i += BSE)
        cellcnt[(size_t)i * NB + b] = min(cur[i], (unsigned)CCAP);
}

// P2: per bucket — compact cells into LDS (wave per cell), count, scan,
// sort in LDS, coalesced writeback to the bucket slab. Emits rowofs/rowcnt
// (absolute into epack) and x_scaled.
__global__ void k_build(unsigned* __restrict__ epack, const unsigned* __restrict__ cellcnt,
                        const float* __restrict__ x,
                        unsigned* __restrict__ rowofs, unsigned* __restrict__ rowcnt,
                        float* __restrict__ x_scaled, int N) {
    __shared__ unsigned stage[FCAP];
    __shared__ unsigned ccnt[NB + 1];
    __shared__ unsigned cofs[NB + 1];
    __shared__ unsigned cnt[BSB];
    __shared__ unsigned sc[BSB];
    __shared__ unsigned cur[BSB];
    int k = blockIdx.x, t = threadIdx.x;           // 512 threads = 8 waves
    size_t kbase = (size_t)k * SLAB;

    // cell counts + exclusive offsets (512-wide scan over 391 entries)
    unsigned v = (t < NB) ? cellcnt[(size_t)k * NB + t] : 0;
    sc[t] = v;
    __syncthreads();
    for (int off = 1; off < BSB; off <<= 1) {
        unsigned u = (t >= off) ? sc[t - off] : 0;
        __syncthreads();
        sc[t] += u;
        __syncthreads();
    }
    if (t < NB) { ccnt[t] = v; cofs[t] = sc[t] - v; }
    if (t == NB - 1) cofs[NB] = sc[t];
    __syncthreads();
    int len = min((int)cofs[NB], FCAP);

    // wave-per-cell compaction: one coalesced 64-lane read per cell
    {
        int wave = t >> 6, lane = t & 63;
        for (int c = wave; c < NB; c += (BSB >> 6)) {
            unsigned cc = ccnt[c];
            if ((unsigned)lane < cc) {
                unsigned o = cofs[c] + lane;
                if ((int)o < len)
                    stage[o] = epack[kbase + (size_t)c * CCAP + lane];
            }
        }
    }
    cnt[t] = 0;
    __syncthreads();

    // per-node degree
    for (int i = t; i < len; i += BSB) atomicAdd(&cnt[stage[i] & (NBW - 1u)], 1u);
    __syncthreads();
    unsigned c = cnt[t];
    sc[t] = c;
    __syncthreads();
    for (int off = 1; off < BSB; off <<= 1) {
        unsigned u = (t >= off) ? sc[t - off] : 0;
        __syncthreads();
        sc[t] += u;
        __syncthreads();
    }
    unsigned excl = sc[t] - c;
    cur[t] = excl;
    int node = k * NBW + t;
    if (node < N) {
        rowofs[node] = (unsigned)kbase + excl;
        rowcnt[node] = c;
        float di = rsqrtf((float)(c + 1));         // +1: self loop
        float4 xv = ((const float4*)x)[node];
        ((float4*)x_scaled)[node] = make_float4(xv.x * di, xv.y * di, xv.z * di, xv.w * di);
    }
    __syncthreads();

    // counting sort: lift to regs, scatter into LDS by node
    unsigned r[RSTG];
    int nr = 0;
    for (int i = t; i < len; i += BSB) r[nr++] = stage[i];
    __syncthreads();
    for (int j = 0; j < nr; ++j) {
        unsigned p = r[j];
        unsigned pos = atomicAdd(&cur[p & (NBW - 1u)], 1u);
        stage[pos] = p >> SH;                       // sorted src lists
    }
    __syncthreads();

    // coalesced writeback into the (now dead) bucket slab
    for (int i = 4 * t; i + 3 < len; i += 4 * BSB)
        *(int4*)(epack + kbase + i) = *(const int4*)&stage[i];
    if (t < (len & 3)) epack[kbase + (len & ~3) + t] = stage[(len & ~3) + t];
}

// P3: pull-mode layer-1 aggregation + fused node math (no atomics).
__global__ void k_agg1(const unsigned* __restrict__ esorted, const unsigned* __restrict__ rowofs,
                       const unsigned* __restrict__ rowcnt,
                       const float* __restrict__ x_scaled,
                       const float* __restrict__ W1, const float* __restrict__ b1,
                       const float* __restrict__ W2,
                       float* __restrict__ z_scaled, int N) {
    int node = blockIdx.x * blockDim.x + threadIdx.x;
    if (node >= N) return;
    unsigned lo = rowofs[node], c = rowcnt[node], hi = lo + c;
    float di = rsqrtf((float)(c + 1));
    const float4* xs4 = (const float4*)x_scaled;
    float4 a0 = xs4[node];                          // self loop
    float4 a1 = make_float4(0.f, 0.f, 0.f, 0.f);
    float4 a2 = make_float4(0.f, 0.f, 0.f, 0.f);
    float4 a3 = make_float4(0.f, 0.f, 0.f, 0.f);
    unsigned i = lo;
    for (; i + 3 < hi; i += 4) {                    // 4 gathers in flight
        float4 v0 = xs4[esorted[i]],     v1 = xs4[esorted[i + 1]];
        float4 v2 = xs4[esorted[i + 2]], v3 = xs4[esorted[i + 3]];
        a0.x += v0.x; a0.y += v0.y; a0.z += v0.z; a0.w += v0.w;
        a1.x += v1.x; a1.y += v1.y; a1.z += v1.z; a1.w += v1.w;
        a2.x += v2.x; a2.y += v2.y; a2.z += v2.z; a2.w += v2.w;
        a3.x += v3.x; a3.y += v3.y; a3.z += v3.z; a3.w += v3.w;
    }
    for (; i < hi; ++i) {
        float4 v = xs4[esorted[i]];
        a0.x += v.x; a0.y += v.y; a0.z += v.z; a0.w += v.w;
    }
    float p0 = di * (a0.x + a1.x + a2.x + a3.x);
    float p1 = di * (a0.y + a1.y + a2.y + a3.y);
    float p2 = di * (a0.z + a1.z + a2.z + a3.z);
    float p3 = di * (a0.w + a1.w + a2.w + a3.w);
    float z = 0.0f;
    #pragma unroll
    for (int cc = 0; cc < 16; ++cc) {
        float h1 = p0 * W1[0 * 16 + cc] + p1 * W1[1 * 16 + cc]
                 + p2 * W1[2 * 16 + cc] + p3 * W1[3 * 16 + cc] + b1[cc];
        h1 = fmaxf(h1, 0.0f);
        z += h1 * W2[cc];
    }
    z_scaled[node] = z * di;
}

// P4: pull-mode layer-2 aggregation (no atomics).
__global__ void k_agg2(const unsigned* __restrict__ esorted, const unsigned* __restrict__ rowofs,
                       const unsigned* __restrict__ rowcnt,
                       const float* __restrict__ z_scaled,
                       const float* __restrict__ b2, float* __restrict__ out, int N) {
    int node = blockIdx.x * blockDim.x + threadIdx.x;
    if (node >= N) return;
    unsigned lo = rowofs[node], c = rowcnt[node], hi = lo + c;
    float di = rsqrtf((float)(c + 1));
    float a0 = z_scaled[node], a1 = 0.f, a2 = 0.f, a3 = 0.f;  // self loop in a0
    unsigned i = lo;
    for (; i + 3 < hi; i += 4) {
        a0 += z_scaled[esorted[i]];
        a1 += z_scaled[esorted[i + 1]];
        a2 += z_scaled[esorted[i + 2]];
        a3 += z_scaled[esorted[i + 3]];
    }
    for (; i < hi; ++i) a0 += z_scaled[esorted[i]];
    out[node] = di * (a0 + a1 + a2 + a3) + b2[0];
}

extern "C" void kernel_launch(void* const* d_in, const int* in_sizes, int n_in,
                              void* d_out, int out_size, void* d_ws, size_t ws_size,
                              hipStream_t stream) {
    const float* x  = (const float*)d_in[0];
    const int*   ei = (const int*)d_in[1];   // [2, E] as int32
    const float* W1 = (const float*)d_in[2];
    const float* b1 = (const float*)d_in[3];
    const float* W2 = (const float*)d_in[4];
    const float* b2 = (const float*)d_in[5];

    const int N = in_sizes[0] / 4;
    const int E = in_sizes[1] / 2;
    const int* src = ei;
    const int* dst = ei + E;
    const int NA = (E + CH - 1) / CH;        // 391 == NB for these sizes

    // Workspace (~45 MB): epack[NB*SLAB] | cellcnt[NB*NB] | rowofs[N] |
    //   rowcnt[N] | x_scaled[N*4] | z_scaled[N]
    char* ws = (char*)d_ws;
    unsigned* epack     = (unsigned*)ws;  ws += (size_t)NB * SLAB * 4;
    unsigned* cellcnt   = (unsigned*)ws;  ws += (size_t)NB * NB * 4;
    unsigned* rowofs    = (unsigned*)ws;  ws += (size_t)N * 4;
    unsigned* rowcnt    = (unsigned*)ws;  ws += (size_t)N * 4;
    float*    x_scaled  = (float*)ws;     ws += (size_t)N * 4 * 4;
    float*    z_scaled  = (float*)ws;     ws += (size_t)N * 4;
    float* out = (float*)d_out;

    k_bin  <<<NA, BSE, 0, stream>>>(src, dst, E, epack, cellcnt);
    k_build<<<NB, BSB, 0, stream>>>(epack, cellcnt, x, rowofs, rowcnt, x_scaled, N);
    k_agg1 <<<(N + 255) / 256, 256, 0, stream>>>(epack, rowofs, rowcnt, x_scaled,
                                                 W1, b1, W2, z_scaled, N);
    k_agg2 <<<(N + 255) / 256, 256, 0, stream>>>(epack, rowofs, rowcnt, z_scaled,
                                                 b2, out, N);
}

// Round 12
// 171.176 us; speedup vs baseline: 1.0859x; 1.0859x over previous
//
#include <hip/hip_runtime.h>

// GCN 2-layer, N=200000, E=3200000.
// R11 post-mortem: padded cells caused 3x r/w amplification -> regressed.
// R12: dense slabs (as R10) but hist+scan replaced by global per-bucket
// cursors: each bin block counts its chunk per bucket in LDS, reserves a
// dense range with ONE global atomicAdd per (block,bucket) (153K atomics
// ~8us), then re-scatters its chunk (L2-hot re-read). 4 launches:
// bin -> build -> agg1 -> agg2.

#define BSE   512    // bin block size
#define CH    8192   // edges per bin block
#define NBW   512    // nodes per bucket
#define SH    9      // log2(NBW)
#define NB    391    // buckets = ceil(200000/512)
#define FCAP  9216   // bucket slab capacity (mean 8184, +11 sigma)
#define BSB   512    // build block size
#define RSTG  ((FCAP + BSB - 1) / BSB)   // 18 staging regs

// P1: bin. Pass 1 counts chunk per bucket (LDS); one global atomicAdd per
// bucket reserves a dense range; pass 2 re-reads chunk (L2-hot) and scatters.
__global__ void k_bin(const int* __restrict__ src, const int* __restrict__ dst,
                      int E, unsigned* __restrict__ gcur,
                      unsigned* __restrict__ epack) {
    __shared__ unsigned cnt[NB];
    __shared__ unsigned cur[NB];
    int b = blockIdx.x, t = threadIdx.x;
    for (int i = t; i < NB; i += BSE) cnt[i] = 0;
    __syncthreads();
    int lo = b * CH, hi = min(E, lo + CH);
    int aligned = (hi - lo) & ~3;
    for (int i = lo + 4 * t; i + 3 < hi; i += 4 * BSE) {
        int4 d4 = *(const int4*)(dst + i);
        atomicAdd(&cnt[((unsigned)d4.x) >> SH], 1u);
        atomicAdd(&cnt[((unsigned)d4.y) >> SH], 1u);
        atomicAdd(&cnt[((unsigned)d4.z) >> SH], 1u);
        atomicAdd(&cnt[((unsigned)d4.w) >> SH], 1u);
    }
    for (int i = lo + aligned + t; i < hi; i += BSE)
        atomicAdd(&cnt[((unsigned)dst[i]) >> SH], 1u);
    __syncthreads();
    for (int i = t; i < NB; i += BSE) {
        unsigned c = cnt[i];
        unsigned ofs = c ? atomicAdd(&gcur[i], c) : 0u;   // dense reservation
        cur[i] = (unsigned)i * FCAP + ofs;
    }
    __syncthreads();
    for (int i = lo + 4 * t; i + 3 < hi; i += 4 * BSE) {
        int4 d4 = *(const int4*)(dst + i);
        int4 s4 = *(const int4*)(src + i);
        unsigned k0 = ((unsigned)d4.x) >> SH, k1 = ((unsigned)d4.y) >> SH;
        unsigned k2 = ((unsigned)d4.z) >> SH, k3 = ((unsigned)d4.w) >> SH;
        unsigned p0 = atomicAdd(&cur[k0], 1u);
        unsigned p1 = atomicAdd(&cur[k1], 1u);
        unsigned p2 = atomicAdd(&cur[k2], 1u);
        unsigned p3 = atomicAdd(&cur[k3], 1u);
        if (p0 < (k0 + 1u) * FCAP) epack[p0] = ((unsigned)s4.x << SH) | (((unsigned)d4.x) & (NBW - 1u));
        if (p1 < (k1 + 1u) * FCAP) epack[p1] = ((unsigned)s4.y << SH) | (((unsigned)d4.y) & (NBW - 1u));
        if (p2 < (k2 + 1u) * FCAP) epack[p2] = ((unsigned)s4.z << SH) | (((unsigned)d4.z) & (NBW - 1u));
        if (p3 < (k3 + 1u) * FCAP) epack[p3] = ((unsigned)s4.w << SH) | (((unsigned)d4.w) & (NBW - 1u));
    }
    for (int i = lo + aligned + t; i < hi; i += BSE) {
        unsigned d = (unsigned)dst[i];
        unsigned k = d >> SH;
        unsigned pos = atomicAdd(&cur[k], 1u);
        if (pos < (k + 1u) * FCAP)
            epack[pos] = ((unsigned)src[i] << SH) | (d & (NBW - 1u));
    }
}

// P2: per bucket — stage dense slab in LDS, count per node, scan, counting
// sort in LDS, coalesced writeback. Emits rowofs/rowcnt and x_scaled.
__global__ void k_build(unsigned* __restrict__ epack, const unsigned* __restrict__ gcur,
                        const float* __restrict__ x,
                        unsigned* __restrict__ rowofs, unsigned* __restrict__ rowcnt,
                        float* __restrict__ x_scaled, int N) {
    __shared__ unsigned stage[FCAP];
    __shared__ unsigned cnt[BSB];
    __shared__ unsigned sc[BSB];
    __shared__ unsigned cur[BSB];
    int k = blockIdx.x, t = threadIdx.x;           // 512 threads
    unsigned base = (unsigned)k * FCAP;
    int len = min((int)gcur[k], FCAP);
    for (int i = 4 * t; i + 3 < len; i += 4 * BSB)
        *(int4*)&stage[i] = *(const int4*)(epack + base + i);
    if (t < (len & 3)) stage[(len & ~3) + t] = epack[base + (len & ~3) + t];
    cnt[t] = 0;
    __syncthreads();
    for (int i = t; i < len; i += BSB) atomicAdd(&cnt[stage[i] & (NBW - 1u)], 1u);
    __syncthreads();
    unsigned c = cnt[t];
    sc[t] = c;
    __syncthreads();
    for (int off = 1; off < BSB; off <<= 1) {
        unsigned u = (t >= off) ? sc[t - off] : 0;
        __syncthreads();
        sc[t] += u;
        __syncthreads();
    }
    unsigned excl = sc[t] - c;
    cur[t] = excl;
    int node = k * NBW + t;
    if (node < N) {
        rowofs[node] = base + excl;
        rowcnt[node] = c;
        float di = rsqrtf((float)(c + 1));         // +1: self loop
        float4 xv = ((const float4*)x)[node];
        ((float4*)x_scaled)[node] = make_float4(xv.x * di, xv.y * di, xv.z * di, xv.w * di);
    }
    __syncthreads();
    unsigned r[RSTG];                               // lift to regs, then sort
    int nr = 0;
    for (int i = t; i < len; i += BSB) r[nr++] = stage[i];
    __syncthreads();
    for (int j = 0; j < nr; ++j) {
        unsigned p = r[j];
        unsigned pos = atomicAdd(&cur[p & (NBW - 1u)], 1u);
        stage[pos] = p >> SH;                       // sorted src lists
    }
    __syncthreads();
    for (int i = 4 * t; i + 3 < len; i += 4 * BSB)  // coalesced writeback
        *(int4*)(epack + base + i) = *(const int4*)&stage[i];
    if (t < (len & 3)) epack[base + (len & ~3) + t] = stage[(len & ~3) + t];
}

// P3: pull-mode layer-1 aggregation + fused node math (no atomics).
__global__ void k_agg1(const unsigned* __restrict__ esorted, const unsigned* __restrict__ rowofs,
                       const unsigned* __restrict__ rowcnt,
                       const float* __restrict__ x_scaled,
                       const float* __restrict__ W1, const float* __restrict__ b1,
                       const float* __restrict__ W2,
                       float* __restrict__ z_scaled, int N) {
    int node = blockIdx.x * blockDim.x + threadIdx.x;
    if (node >= N) return;
    unsigned lo = rowofs[node], c = rowcnt[node], hi = lo + c;
    float di = rsqrtf((float)(c + 1));
    const float4* xs4 = (const float4*)x_scaled;
    float4 a0 = xs4[node];                          // self loop
    float4 a1 = make_float4(0.f, 0.f, 0.f, 0.f);
    float4 a2 = make_float4(0.f, 0.f, 0.f, 0.f);
    float4 a3 = make_float4(0.f, 0.f, 0.f, 0.f);
    unsigned i = lo;
    for (; i + 3 < hi; i += 4) {                    // 4 gathers in flight
        float4 v0 = xs4[esorted[i]],     v1 = xs4[esorted[i + 1]];
        float4 v2 = xs4[esorted[i + 2]], v3 = xs4[esorted[i + 3]];
        a0.x += v0.x; a0.y += v0.y; a0.z += v0.z; a0.w += v0.w;
        a1.x += v1.x; a1.y += v1.y; a1.z += v1.z; a1.w += v1.w;
        a2.x += v2.x; a2.y += v2.y; a2.z += v2.z; a2.w += v2.w;
        a3.x += v3.x; a3.y += v3.y; a3.z += v3.z; a3.w += v3.w;
    }
    for (; i < hi; ++i) {
        float4 v = xs4[esorted[i]];
        a0.x += v.x; a0.y += v.y; a0.z += v.z; a0.w += v.w;
    }
    float p0 = di * (a0.x + a1.x + a2.x + a3.x);
    float p1 = di * (a0.y + a1.y + a2.y + a3.y);
    float p2 = di * (a0.z + a1.z + a2.z + a3.z);
    float p3 = di * (a0.w + a1.w + a2.w + a3.w);
    float z = 0.0f;
    #pragma unroll
    for (int cc = 0; cc < 16; ++cc) {
        float h1 = p0 * W1[0 * 16 + cc] + p1 * W1[1 * 16 + cc]
                 + p2 * W1[2 * 16 + cc] + p3 * W1[3 * 16 + cc] + b1[cc];
        h1 = fmaxf(h1, 0.0f);
        z += h1 * W2[cc];
    }
    z_scaled[node] = z * di;
}

// P4: pull-mode layer-2 aggregation (no atomics).
__global__ void k_agg2(const unsigned* __restrict__ esorted, const unsigned* __restrict__ rowofs,
                       const unsigned* __restrict__ rowcnt,
                       const float* __restrict__ z_scaled,
                       const float* __restrict__ b2, float* __restrict__ out, int N) {
    int node = blockIdx.x * blockDim.x + threadIdx.x;
    if (node >= N) return;
    unsigned lo = rowofs[node], c = rowcnt[node], hi = lo + c;
    float di = rsqrtf((float)(c + 1));
    float a0 = z_scaled[node], a1 = 0.f, a2 = 0.f, a3 = 0.f;  // self loop in a0
    unsigned i = lo;
    for (; i + 3 < hi; i += 4) {
        a0 += z_scaled[esorted[i]];
        a1 += z_scaled[esorted[i + 1]];
        a2 += z_scaled[esorted[i + 2]];
        a3 += z_scaled[esorted[i + 3]];
    }
    for (; i < hi; ++i) a0 += z_scaled[esorted[i]];
    out[node] = di * (a0 + a1 + a2 + a3) + b2[0];
}

extern "C" void kernel_launch(void* const* d_in, const int* in_sizes, int n_in,
                              void* d_out, int out_size, void* d_ws, size_t ws_size,
                              hipStream_t stream) {
    const float* x  = (const float*)d_in[0];
    const int*   ei = (const int*)d_in[1];   // [2, E] as int32
    const float* W1 = (const float*)d_in[2];
    const float* b1 = (const float*)d_in[3];
    const float* W2 = (const float*)d_in[4];
    const float* b2 = (const float*)d_in[5];

    const int N = in_sizes[0] / 4;
    const int E = in_sizes[1] / 2;
    const int* src = ei;
    const int* dst = ei + E;
    const int NA = (E + CH - 1) / CH;        // 391

    // Workspace (~16.5 MB): gcur[NB] | epack[NB*FCAP] | rowofs[N] | rowcnt[N] |
    //   x_scaled[N*4] | z_scaled[N]
    char* ws = (char*)d_ws;
    unsigned* gcur      = (unsigned*)ws;  ws += 4096;   // padded for alignment
    unsigned* epack     = (unsigned*)ws;  ws += (size_t)NB * FCAP * 4;
    unsigned* rowofs    = (unsigned*)ws;  ws += (size_t)N * 4;
    unsigned* rowcnt    = (unsigned*)ws;  ws += (size_t)N * 4;
    float*    x_scaled  = (float*)ws;     ws += (size_t)N * 4 * 4;
    float*    z_scaled  = (float*)ws;     ws += (size_t)N * 4;
    float* out = (float*)d_out;

    hipMemsetAsync(gcur, 0, NB * sizeof(unsigned), stream);
    k_bin  <<<NA, BSE, 0, stream>>>(src, dst, E, gcur, epack);
    k_build<<<NB, BSB, 0, stream>>>(epack, gcur, x, rowofs, rowcnt, x_scaled, N);
    k_agg1 <<<(N + 255) / 256, 256, 0, stream>>>(epack, rowofs, rowcnt, x_scaled,
                                                 W1, b1, W2, z_scaled, N);
    k_agg2 <<<(N + 255) / 256, 256, 0, stream>>>(epack, rowofs, rowcnt, z_scaled,
                                                 b2, out, N);
}

// Round 13
// 168.501 us; speedup vs baseline: 1.1032x; 1.0159x over previous
//
#include <hip/hip_runtime.h>

// GCN 2-layer, N=200000, E=3200000.
// R12 post-mortem: k_bin's cost is partial-line write transactions (runs of
// ~21 words at arbitrary offsets; each line RMW-touched by ~3 blocks), not
// write bytes. R13: CH=16384 + reservations rounded to 16 words (64B lines),
// sentinel-padded (0xFFFFFFFF). Every slab line written once, fully.
// k_build skips sentinels. 4 launches: bin -> build -> agg1 -> agg2.

#define BSE   512     // bin block size
#define CH    16384   // edges per bin block
#define NBW   512     // nodes per bucket
#define SH    9       // log2(NBW)
#define NB    391     // buckets = ceil(200000/512)
#define FCAP  10752   // slab capacity (valid mean 8184 + pad mean ~1470, +10 sigma)
#define BSB   512     // build block size
#define RSTG  ((FCAP + BSB - 1) / BSB)   // 21 staging regs
#define NOEDGE 0xFFFFFFFFu

// P1: bin. Pass 1: LDS per-bucket count. Reserve 16-word-aligned dense range
// per (block,bucket) via one global atomicAdd. Pass 2: scatter (L2-hot
// re-read). Tail: sentinel-fill the pad while lines are hot.
__global__ void k_bin(const int* __restrict__ src, const int* __restrict__ dst,
                      int E, unsigned* __restrict__ gcur,
                      unsigned* __restrict__ epack) {
    __shared__ unsigned cnt[NB];
    __shared__ unsigned cur[NB];
    __shared__ unsigned basec[NB];
    int b = blockIdx.x, t = threadIdx.x;
    for (int i = t; i < NB; i += BSE) cnt[i] = 0;
    __syncthreads();
    int lo = b * CH, hi = min(E, lo + CH);
    int aligned = (hi - lo) & ~3;
    for (int i = lo + 4 * t; i + 3 < hi; i += 4 * BSE) {
        int4 d4 = *(const int4*)(dst + i);
        atomicAdd(&cnt[((unsigned)d4.x) >> SH], 1u);
        atomicAdd(&cnt[((unsigned)d4.y) >> SH], 1u);
        atomicAdd(&cnt[((unsigned)d4.z) >> SH], 1u);
        atomicAdd(&cnt[((unsigned)d4.w) >> SH], 1u);
    }
    for (int i = lo + aligned + t; i < hi; i += BSE)
        atomicAdd(&cnt[((unsigned)dst[i]) >> SH], 1u);
    __syncthreads();
    for (int i = t; i < NB; i += BSE) {
        unsigned c = cnt[i];
        unsigned pad = (c + 15u) & ~15u;               // 64B-aligned reservation
        unsigned ofs = pad ? atomicAdd(&gcur[i], pad) : 0u;
        unsigned base = (unsigned)i * FCAP + ofs;
        basec[i] = base;
        cur[i] = base;
    }
    __syncthreads();
    for (int i = lo + 4 * t; i + 3 < hi; i += 4 * BSE) {
        int4 d4 = *(const int4*)(dst + i);
        int4 s4 = *(const int4*)(src + i);
        unsigned k0 = ((unsigned)d4.x) >> SH, k1 = ((unsigned)d4.y) >> SH;
        unsigned k2 = ((unsigned)d4.z) >> SH, k3 = ((unsigned)d4.w) >> SH;
        unsigned p0 = atomicAdd(&cur[k0], 1u);
        unsigned p1 = atomicAdd(&cur[k1], 1u);
        unsigned p2 = atomicAdd(&cur[k2], 1u);
        unsigned p3 = atomicAdd(&cur[k3], 1u);
        if (p0 < (k0 + 1u) * FCAP) epack[p0] = ((unsigned)s4.x << SH) | (((unsigned)d4.x) & (NBW - 1u));
        if (p1 < (k1 + 1u) * FCAP) epack[p1] = ((unsigned)s4.y << SH) | (((unsigned)d4.y) & (NBW - 1u));
        if (p2 < (k2 + 1u) * FCAP) epack[p2] = ((unsigned)s4.z << SH) | (((unsigned)d4.z) & (NBW - 1u));
        if (p3 < (k3 + 1u) * FCAP) epack[p3] = ((unsigned)s4.w << SH) | (((unsigned)d4.w) & (NBW - 1u));
    }
    for (int i = lo + aligned + t; i < hi; i += BSE) {
        unsigned d = (unsigned)dst[i];
        unsigned k = d >> SH;
        unsigned pos = atomicAdd(&cur[k], 1u);
        if (pos < (k + 1u) * FCAP)
            epack[pos] = ((unsigned)src[i] << SH) | (d & (NBW - 1u));
    }
    __syncthreads();
    // sentinel-fill the pad of each cell (lines still L2-hot)
    for (int i = t; i < NB; i += BSE) {
        unsigned end = basec[i] + ((cnt[i] + 15u) & ~15u);
        unsigned kend = ((unsigned)i + 1u) * FCAP;
        if (end > kend) end = kend;
        for (unsigned p = cur[i]; p < end; ++p) epack[p] = NOEDGE;
    }
}

// P2: per bucket — stage slab in LDS, count per node (skip sentinels), scan,
// counting sort in LDS, coalesced writeback. Emits rowofs/rowcnt, x_scaled.
__global__ void k_build(unsigned* __restrict__ epack, const unsigned* __restrict__ gcur,
                        const float* __restrict__ x,
                        unsigned* __restrict__ rowofs, unsigned* __restrict__ rowcnt,
                        float* __restrict__ x_scaled, int N) {
    __shared__ unsigned stage[FCAP];
    __shared__ unsigned cnt[BSB];
    __shared__ unsigned sc[BSB];
    __shared__ unsigned cur[BSB];
    int k = blockIdx.x, t = threadIdx.x;           // 512 threads
    unsigned base = (unsigned)k * FCAP;
    int len = min((int)gcur[k], FCAP);             // includes sentinel pad
    for (int i = 4 * t; i + 3 < len; i += 4 * BSB)
        *(int4*)&stage[i] = *(const int4*)(epack + base + i);
    if (t < (len & 3)) stage[(len & ~3) + t] = epack[base + (len & ~3) + t];
    cnt[t] = 0;
    __syncthreads();
    for (int i = t; i < len; i += BSB) {
        unsigned p = stage[i];
        if (p != NOEDGE) atomicAdd(&cnt[p & (NBW - 1u)], 1u);
    }
    __syncthreads();
    unsigned c = cnt[t];
    sc[t] = c;
    __syncthreads();
    for (int off = 1; off < BSB; off <<= 1) {
        unsigned u = (t >= off) ? sc[t - off] : 0;
        __syncthreads();
        sc[t] += u;
        __syncthreads();
    }
    unsigned excl = sc[t] - c;
    cur[t] = excl;
    int node = k * NBW + t;
    if (node < N) {
        rowofs[node] = base + excl;
        rowcnt[node] = c;
        float di = rsqrtf((float)(c + 1));         // +1: self loop
        float4 xv = ((const float4*)x)[node];
        ((float4*)x_scaled)[node] = make_float4(xv.x * di, xv.y * di, xv.z * di, xv.w * di);
    }
    __syncthreads();
    int lenv = (int)sc[BSB - 1];                   // valid edge count
    unsigned r[RSTG];                               // lift to regs, then sort
    int nr = 0;
    for (int i = t; i < len; i += BSB) r[nr++] = stage[i];
    __syncthreads();
    for (int j = 0; j < nr; ++j) {
        unsigned p = r[j];
        if (p != NOEDGE) {
            unsigned pos = atomicAdd(&cur[p & (NBW - 1u)], 1u);
            stage[pos] = p >> SH;                   // sorted src lists
        }
    }
    __syncthreads();
    for (int i = 4 * t; i + 3 < lenv; i += 4 * BSB) // coalesced writeback
        *(int4*)(epack + base + i) = *(const int4*)&stage[i];
    if (t < (lenv & 3)) epack[base + (lenv & ~3) + t] = stage[(lenv & ~3) + t];
}

// P3: pull-mode layer-1 aggregation + fused node math (no atomics).
__global__ void k_agg1(const unsigned* __restrict__ esorted, const unsigned* __restrict__ rowofs,
                       const unsigned* __restrict__ rowcnt,
                       const float* __restrict__ x_scaled,
                       const float* __restrict__ W1, const float* __restrict__ b1,
                       const float* __restrict__ W2,
                       float* __restrict__ z_scaled, int N) {
    int node = blockIdx.x * blockDim.x + threadIdx.x;
    if (node >= N) return;
    unsigned lo = rowofs[node], c = rowcnt[node], hi = lo + c;
    float di = rsqrtf((float)(c + 1));
    const float4* xs4 = (const float4*)x_scaled;
    float4 a0 = xs4[node];                          // self loop
    float4 a1 = make_float4(0.f, 0.f, 0.f, 0.f);
    float4 a2 = make_float4(0.f, 0.f, 0.f, 0.f);
    float4 a3 = make_float4(0.f, 0.f, 0.f, 0.f);
    unsigned i = lo;
    for (; i + 3 < hi; i += 4) {                    // 4 gathers in flight
        float4 v0 = xs4[esorted[i]],     v1 = xs4[esorted[i + 1]];
        float4 v2 = xs4[esorted[i + 2]], v3 = xs4[esorted[i + 3]];
        a0.x += v0.x; a0.y += v0.y; a0.z += v0.z; a0.w += v0.w;
        a1.x += v1.x; a1.y += v1.y; a1.z += v1.z; a1.w += v1.w;
        a2.x += v2.x; a2.y += v2.y; a2.z += v2.z; a2.w += v2.w;
        a3.x += v3.x; a3.y += v3.y; a3.z += v3.z; a3.w += v3.w;
    }
    for (; i < hi; ++i) {
        float4 v = xs4[esorted[i]];
        a0.x += v.x; a0.y += v.y; a0.z += v.z; a0.w += v.w;
    }
    float p0 = di * (a0.x + a1.x + a2.x + a3.x);
    float p1 = di * (a0.y + a1.y + a2.y + a3.y);
    float p2 = di * (a0.z + a1.z + a2.z + a3.z);
    float p3 = di * (a0.w + a1.w + a2.w + a3.w);
    float z = 0.0f;
    #pragma unroll
    for (int cc = 0; cc < 16; ++cc) {
        float h1 = p0 * W1[0 * 16 + cc] + p1 * W1[1 * 16 + cc]
                 + p2 * W1[2 * 16 + cc] + p3 * W1[3 * 16 + cc] + b1[cc];
        h1 = fmaxf(h1, 0.0f);
        z += h1 * W2[cc];
    }
    z_scaled[node] = z * di;
}

// P4: pull-mode layer-2 aggregation (no atomics).
__global__ void k_agg2(const unsigned* __restrict__ esorted, const unsigned* __restrict__ rowofs,
                       const unsigned* __restrict__ rowcnt,
                       const float* __restrict__ z_scaled,
                       const float* __restrict__ b2, float* __restrict__ out, int N) {
    int node = blockIdx.x * blockDim.x + threadIdx.x;
    if (node >= N) return;
    unsigned lo = rowofs[node], c = rowcnt[node], hi = lo + c;
    float di = rsqrtf((float)(c + 1));
    float a0 = z_scaled[node], a1 = 0.f, a2 = 0.f, a3 = 0.f;  // self loop in a0
    unsigned i = lo;
    for (; i + 3 < hi; i += 4) {
        a0 += z_scaled[esorted[i]];
        a1 += z_scaled[esorted[i + 1]];
        a2 += z_scaled[esorted[i + 2]];
        a3 += z_scaled[esorted[i + 3]];
    }
    for (; i < hi; ++i) a0 += z_scaled[esorted[i]];
    out[node] = di * (a0 + a1 + a2 + a3) + b2[0];
}

extern "C" void kernel_launch(void* const* d_in, const int* in_sizes, int n_in,
                              void* d_out, int out_size, void* d_ws, size_t ws_size,
                              hipStream_t stream) {
    const float* x  = (const float*)d_in[0];
    const int*   ei = (const int*)d_in[1];   // [2, E] as int32
    const float* W1 = (const float*)d_in[2];
    const float* b1 = (const float*)d_in[3];
    const float* W2 = (const float*)d_in[4];
    const float* b2 = (const float*)d_in[5];

    const int N = in_sizes[0] / 4;
    const int E = in_sizes[1] / 2;
    const int* src = ei;
    const int* dst = ei + E;
    const int NA = (E + CH - 1) / CH;        // 196

    // Workspace (~19 MB): gcur | epack[NB*FCAP] | rowofs[N] | rowcnt[N] |
    //   x_scaled[N*4] | z_scaled[N]
    char* ws = (char*)d_ws;
    unsigned* gcur      = (unsigned*)ws;  ws += 4096;
    unsigned* epack     = (unsigned*)ws;  ws += (size_t)NB * FCAP * 4;
    unsigned* rowofs    = (unsigned*)ws;  ws += (size_t)N * 4;
    unsigned* rowcnt    = (unsigned*)ws;  ws += (size_t)N * 4;
    float*    x_scaled  = (float*)ws;     ws += (size_t)N * 4 * 4;
    float*    z_scaled  = (float*)ws;     ws += (size_t)N * 4;
    float* out = (float*)d_out;

    hipMemsetAsync(gcur, 0, NB * sizeof(unsigned), stream);
    k_bin  <<<NA, BSE, 0, stream>>>(src, dst, E, gcur, epack);
    k_build<<<NB, BSB, 0, stream>>>(epack, gcur, x, rowofs, rowcnt, x_scaled, N);
    k_agg1 <<<(N + 255) / 256, 256, 0, stream>>>(epack, rowofs, rowcnt, x_scaled,
                                                 W1, b1, W2, z_scaled, N);
    k_agg2 <<<(N + 255) / 256, 256, 0, stream>>>(epack, rowofs, rowcnt, z_scaled,
                                                 b2, out, N);
}